// Round 3
// baseline (300.882 us; speedup 1.0000x reference)
//
#include <hip/hip_runtime.h>
#include <hip/hip_bf16.h>

typedef short bf16x8 __attribute__((ext_vector_type(8)));
typedef float f32x4 __attribute__((ext_vector_type(4)));

#define MFMA16(a, b, c) __builtin_amdgcn_mfma_f32_16x16x32_bf16(a, b, c, 0, 0, 0)

#define NB 4
#define NC 256
#define NSP 4096
#define LOG2E 1.4426950408889634f

__device__ __forceinline__ unsigned short f2bf(float f) {
    return (unsigned short)((__float_as_uint(f) + 0x8000u) >> 16);
}
// packed pair: (bf(hi)<<16)|bf(lo) via v_perm_b32 — 3 VALU ops
__device__ __forceinline__ unsigned pk2bf(float hi, float lo) {
    return __builtin_amdgcn_perm(__float_as_uint(hi) + 0x8000u,
                                 __float_as_uint(lo) + 0x8000u, 0x07060302u);
}

// ---------------------------------------------------------------------------
// prep_w: weights -> bf16, natural [o][ci] layout. (proven verbatim)
// ---------------------------------------------------------------------------
__global__ __launch_bounds__(256) void prep_w(
    const float* __restrict__ Qw, const float* __restrict__ Kw,
    const float* __restrict__ Vw,
    unsigned short* __restrict__ Qwbf, unsigned short* __restrict__ Kwbf,
    unsigned short* __restrict__ Vwbf)
{
    int i = blockIdx.x * 256 + threadIdx.x;   // 0..16383
    {
        const float4* vs = (const float4*)(Vw + (size_t)i * 8);
        float4 a = vs[0], c = vs[1];
        int4 st;
        st.x = (int)pk2bf(a.y, a.x); st.y = (int)pk2bf(a.w, a.z);
        st.z = (int)pk2bf(c.y, c.x); st.w = (int)pk2bf(c.w, c.z);
        *(int4*)(Vwbf + (size_t)i * 8) = st;
    }
    if (i < 2048) {
        const float4* qs = (const float4*)(Qw + (size_t)i * 8);
        float4 a = qs[0], c = qs[1];
        int4 st;
        st.x = (int)pk2bf(a.y, a.x); st.y = (int)pk2bf(a.w, a.z);
        st.z = (int)pk2bf(c.y, c.x); st.w = (int)pk2bf(c.w, c.z);
        *(int4*)(Qwbf + (size_t)i * 8) = st;
    }
    if (i < 1024) {
        const float4* ks = (const float4*)(Kw + (size_t)i * 8);
        float4 a = ks[0], c = ks[1];
        int4 st;
        st.x = (int)pk2bf(a.y, a.x); st.y = (int)pk2bf(a.w, a.z);
        st.z = (int)pk2bf(c.y, c.x); st.w = (int)pk2bf(c.w, c.z);
        *(int4*)(Kwbf + (size_t)i * 8) = st;
    }
}

// ---------------------------------------------------------------------------
// proj_fused: ONE launch, PARITY-interleaved block roles (R2 post-mortem:
// contiguous role runs caused CU load imbalance, +20us vs separate launches).
//   blockIdx.x even -> fused Q+V projection over concat(ef,sf)
//   blockIdx.x odd  -> K projection over attn
// Adjacent blocks (same CU neighborhood) get one long + one short role.
// ---------------------------------------------------------------------------
__global__ __launch_bounds__(256) void proj_fused(
    const float* __restrict__ ef, const float* __restrict__ sf,
    const float* __restrict__ attnp,
    const unsigned short* __restrict__ Qwbf, const float* __restrict__ Qb,
    const unsigned short* __restrict__ Kwbf, const float* __restrict__ Kb,
    const unsigned short* __restrict__ Vwbf, const float* __restrict__ Vb,
    unsigned short* __restrict__ qws, unsigned short* __restrict__ kws,
    unsigned short* __restrict__ vws)
{
    __shared__ __align__(16) unsigned short xt[32][72];

    int t = threadIdx.x;
    int w = t >> 6, lane = t & 63, quad = lane >> 4, l15 = lane & 15;
    int b = blockIdx.y;
    int ci = t & 63, sm = t >> 6;
    int mi = w >> 1, oh = w & 1;
    int role = blockIdx.x & 1;
    int mt = blockIdx.x >> 1, m0 = mt * 32;

    if (role == 0) {
        // ---------------- Q+V role ----------------
        f32x4 zero = {0.f, 0.f, 0.f, 0.f};
        f32x4 acc[2][4];
#pragma unroll
        for (int m = 0; m < 2; ++m)
#pragma unroll
            for (int ot = 0; ot < 4; ++ot) acc[m][ot] = zero;
        f32x4 qacc = zero;

        const float* s0p = ef + ((size_t)(b * NC) + ci) * NSP + m0 + sm * 8;
        float4 x0 = *(const float4*)s0p;
        float4 x1 = *(const float4*)(s0p + 4);

        for (int c = 0; c < 8; ++c) {
            float4 n0 = x0, n1 = x1;
            if (c < 7) {
                int cn = c + 1;
                const float* sn = (cn < 4 ? ef : sf) +
                                  ((size_t)(b * NC) + (cn & 3) * 64 + ci) * NSP + m0 + sm * 8;
                n0 = *(const float4*)sn;
                n1 = *(const float4*)(sn + 4);
            }
            __syncthreads();
            unsigned short* xd = &xt[sm * 8][ci];
            xd[0]   = f2bf(x0.x); xd[72]  = f2bf(x0.y);
            xd[144] = f2bf(x0.z); xd[216] = f2bf(x0.w);
            xd[288] = f2bf(x1.x); xd[360] = f2bf(x1.y);
            xd[432] = f2bf(x1.z); xd[504] = f2bf(x1.w);
            __syncthreads();
            int ci0 = c * 64;
#pragma unroll
            for (int ks = 0; ks < 2; ++ks) {
                bf16x8 a0 = *(const bf16x8*)&xt[l15][ks * 32 + quad * 8];
                bf16x8 a1 = *(const bf16x8*)&xt[16 + l15][ks * 32 + quad * 8];
                bf16x8 bq = *(const bf16x8*)(Qwbf + (size_t)(oh * 16 + l15) * 512 + ci0 + ks * 32 + quad * 8);
                qacc = MFMA16(mi ? a1 : a0, bq, qacc);
#pragma unroll
                for (int ot = 0; ot < 4; ++ot) {
                    bf16x8 bv = *(const bf16x8*)(Vwbf + (size_t)(w * 64 + ot * 16 + l15) * 512 + ci0 + ks * 32 + quad * 8);
                    acc[0][ot] = MFMA16(a0, bv, acc[0][ot]);
                    acc[1][ot] = MFMA16(a1, bv, acc[1][ot]);
                }
            }
            x0 = n0; x1 = n1;
        }

        // V epilogue
#pragma unroll
        for (int ot = 0; ot < 4; ++ot) {
            int ch = w * 64 + ot * 16 + l15;
            float bias = Vb[ch];
            unsigned* vp = (unsigned*)(vws + ((size_t)((b * 128 + mt) * 256 + ch)) * 32);
#pragma unroll
            for (int r = 0; r < 4; ++r)
                vp[quad * 4 + r] = pk2bf(acc[1][ot][r] + bias, acc[0][ot][r] + bias);
        }

        // Q epilogue
        int o = oh * 16 + l15;
        float bb = Qb[o];
#pragma unroll
        for (int r = 0; r < 4; ++r) {
            int m = m0 + mi * 16 + quad * 4 + r;
            qws[((size_t)(b * NSP) + m) * 32 + o] = f2bf((qacc[r] + bb) * LOG2E);
        }
    } else {
        // ---------------- K role ----------------
        f32x4 acc = {0.f, 0.f, 0.f, 0.f};

        const float* s0p = attnp + ((size_t)(b * NC) + ci) * NSP + m0 + sm * 8;
        float4 x0 = *(const float4*)s0p;
        float4 x1 = *(const float4*)(s0p + 4);

        for (int c = 0; c < 4; ++c) {
            float4 n0 = x0, n1 = x1;
            if (c < 3) {
                const float* sn = attnp + ((size_t)(b * NC) + (c + 1) * 64 + ci) * NSP + m0 + sm * 8;
                n0 = *(const float4*)sn;
                n1 = *(const float4*)(sn + 4);
            }
            __syncthreads();
            unsigned short* xd = &xt[sm * 8][ci];
            xd[0]   = f2bf(x0.x); xd[72]  = f2bf(x0.y);
            xd[144] = f2bf(x0.z); xd[216] = f2bf(x0.w);
            xd[288] = f2bf(x1.x); xd[360] = f2bf(x1.y);
            xd[432] = f2bf(x1.z); xd[504] = f2bf(x1.w);
            __syncthreads();
            int ci0 = c * 64;
#pragma unroll
            for (int ks = 0; ks < 2; ++ks) {
                bf16x8 a  = *(const bf16x8*)&xt[mi * 16 + l15][ks * 32 + quad * 8];
                bf16x8 bk = *(const bf16x8*)(Kwbf + (size_t)(oh * 16 + l15) * 256 + ci0 + ks * 32 + quad * 8);
                acc = MFMA16(a, bk, acc);
            }
            x0 = n0; x1 = n1;
        }

        int o = oh * 16 + l15;
        float bb = Kb[o];
#pragma unroll
        for (int r = 0; r < 4; ++r) {
            int m = m0 + mi * 16 + quad * 4 + r;
            kws[((size_t)(b * NSP) + m) * 32 + o] = f2bf(acc[r] + bb);
        }
    }
}

// ---------------------------------------------------------------------------
// attention: 32 queries/block -> 512 blocks (2 blocks/CU, 4 waves/SIMD; R2
// showed grid=256 capped occupancy at 2 waves/SIMD). 512 thr = 2 key-groups
// x 4 waves; wave (qh=w&1, kh=w>>1) does 16q x 32k QK (2 MFMAs) on key-tile
// kh; PV channel slice w*64 unchanged (16 MFMAs). acc 64->32 VGPRs.
// No setprio (R2: -4us on this lockstep structure).
// Merge reuses retired Plds: 128ch x 36 f32 = 18432 B == sizeof(Plds).
// ---------------------------------------------------------------------------
__global__ __launch_bounds__(512, 4) void attention(
    const unsigned short* __restrict__ qws, const unsigned short* __restrict__ kws,
    const unsigned short* __restrict__ vws, const float* __restrict__ ef,
    const float* __restrict__ gamma, float* __restrict__ out)
{
    __shared__ __align__(16) unsigned short Plds[2][2][32 * 72];   // 18432 B
    __shared__ __align__(16) float denl[2][2][32];

    int t = threadIdx.x;
    int g = t >> 8, tl = t & 255;
    int w = tl >> 6, lane = tl & 63, quad = lane >> 4, l15 = lane & 15;
    int qh = w & 1, kh = w >> 1;
    int b = blockIdx.x >> 7, m0 = (blockIdx.x & 127) << 5;

    const unsigned short* kbase = kws + (size_t)(b * NSP) * 32;
    const unsigned short* vbase = vws + (size_t)(b * 128) * 8192;

    bf16x8 qf = *(const bf16x8*)(qws + ((size_t)(b * NSP) + m0 + qh * 16 + l15) * 32 + quad * 8);

    f32x4 zero = {0.f, 0.f, 0.f, 0.f};
    f32x4 acc[2][4];
#pragma unroll
    for (int i = 0; i < 2; ++i)
#pragma unroll
        for (int j = 0; j < 4; ++j) acc[i][j] = zero;
    float lp0 = 0.f, lp1 = 0.f, lp2 = 0.f, lp3 = 0.f;

    // first tiles: group g, iter 0 covers tiles T0=g*64, T0+1; this wave's
    // QK tile is T0+kh; PV needs both tiles.
    bf16x8 kf[2];
#pragma unroll
    for (int j = 0; j < 2; ++j)
        kf[j] = *(const bf16x8*)(kbase + (size_t)((g * 64 + kh) * 32 + j * 16 + l15) * 32 + quad * 8);
    bf16x8 vf[2][4];
#pragma unroll
    for (int h = 0; h < 2; ++h)
#pragma unroll
        for (int cc = 0; cc < 4; ++cc)
            vf[h][cc] = *(const bf16x8*)(vbase + (size_t)(g * 64 + h) * 8192 + (w * 64 + cc * 16 + l15) * 32 + quad * 8);

    for (int it = 0; it < 32; ++it) {
        int buf = it & 1;
        f32x4 s0 = MFMA16(qf, kf[0], zero);
        f32x4 s1 = MFMA16(qf, kf[1], zero);

        float e0[4], e1[4];
#pragma unroll
        for (int r = 0; r < 4; ++r) {
            e0[r] = __builtin_amdgcn_exp2f(s0[r]);
            e1[r] = __builtin_amdgcn_exp2f(s1[r]);
        }
        lp0 += e0[0] + e1[0];
        lp1 += e0[1] + e1[1];
        lp2 += e0[2] + e1[2];
        lp3 += e0[3] + e1[3];

        // P row = qh*16 + quad*4 + r; cols kh*32 + pair(l15): short[2j]=key j,
        // short[2j+1]=key 16+j of tile (matches vws pairing).
        unsigned short* pd = &Plds[g][buf][(qh * 16 + quad * 4) * 72 + kh * 32 + 2 * l15];
#pragma unroll
        for (int r = 0; r < 4; ++r)
            *(unsigned*)(pd + r * 72) = pk2bf(e1[r], e0[r]);

        // prefetch next iteration
        int itn = it + 1 < 32 ? it + 1 : 31;
        int Tn = g * 64 + 2 * itn;
#pragma unroll
        for (int j = 0; j < 2; ++j)
            kf[j] = *(const bf16x8*)(kbase + (size_t)((Tn + kh) * 32 + j * 16 + l15) * 32 + quad * 8);
        bf16x8 vfn[2][4];
#pragma unroll
        for (int h = 0; h < 2; ++h)
#pragma unroll
            for (int cc = 0; cc < 4; ++cc)
                vfn[h][cc] = *(const bf16x8*)(vbase + (size_t)(Tn + h) * 8192 + (w * 64 + cc * 16 + l15) * 32 + quad * 8);

        __syncthreads();

#pragma unroll
        for (int h = 0; h < 2; ++h) {
            bf16x8 pa0 = *(const bf16x8*)&Plds[g][buf][(0  + l15) * 72 + h * 32 + quad * 8];
            bf16x8 pa1 = *(const bf16x8*)&Plds[g][buf][(16 + l15) * 72 + h * 32 + quad * 8];
#pragma unroll
            for (int cc = 0; cc < 4; ++cc) {
                acc[0][cc] = MFMA16(pa0, vf[h][cc], acc[0][cc]);
                acc[1][cc] = MFMA16(pa1, vf[h][cc], acc[1][cc]);
            }
        }
#pragma unroll
        for (int h = 0; h < 2; ++h)
#pragma unroll
            for (int cc = 0; cc < 4; ++cc) vf[h][cc] = vfn[h][cc];
    }

    // per-(group,key-half) denominator partials for this wave's 16 q rows
    lp0 += __shfl_xor(lp0, 1); lp0 += __shfl_xor(lp0, 2); lp0 += __shfl_xor(lp0, 4); lp0 += __shfl_xor(lp0, 8);
    lp1 += __shfl_xor(lp1, 1); lp1 += __shfl_xor(lp1, 2); lp1 += __shfl_xor(lp1, 4); lp1 += __shfl_xor(lp1, 8);
    lp2 += __shfl_xor(lp2, 1); lp2 += __shfl_xor(lp2, 2); lp2 += __shfl_xor(lp2, 4); lp2 += __shfl_xor(lp2, 8);
    lp3 += __shfl_xor(lp3, 1); lp3 += __shfl_xor(lp3, 2); lp3 += __shfl_xor(lp3, 4); lp3 += __shfl_xor(lp3, 8);
    if (l15 == 0) {
        int base = qh * 16 + quad * 4;
        denl[g][kh][base + 0] = lp0; denl[g][kh][base + 1] = lp1;
        denl[g][kh][base + 2] = lp2; denl[g][kh][base + 3] = lp3;
    }
    __syncthreads();   // A: all Plds reads done; denl visible; Plds space free

    // Two-pass merge through retired Plds: per half, 128ch x 32q f32.
    float (*mrgO)[36] = (float (*)[36])&Plds[0][0][0];
    float gam = gamma[0];

#pragma unroll
    for (int half = 0; half < 2; ++half) {
        if (g == 1) {
#pragma unroll
            for (int qc2 = 0; qc2 < 2; ++qc2)
#pragma unroll
                for (int c2 = 0; c2 < 2; ++c2)
                    *(f32x4*)&mrgO[w * 32 + c2 * 16 + l15][qc2 * 16 + quad * 4] = acc[qc2][half * 2 + c2];
        }
        __syncthreads();
        if (g == 0) {
#pragma unroll
            for (int qc2 = 0; qc2 < 2; ++qc2) {
                int qb = qc2 * 16 + quad * 4;
                float4 d00 = *(const float4*)&denl[0][0][qb];
                float4 d01 = *(const float4*)&denl[0][1][qb];
                float4 d10 = *(const float4*)&denl[1][0][qb];
                float4 d11 = *(const float4*)&denl[1][1][qb];
                float r0 = gam / ((d00.x + d01.x) + (d10.x + d11.x));
                float r1 = gam / ((d00.y + d01.y) + (d10.y + d11.y));
                float r2 = gam / ((d00.z + d01.z) + (d10.z + d11.z));
                float r3 = gam / ((d00.w + d01.w) + (d10.w + d11.w));
#pragma unroll
                for (int c2 = 0; c2 < 2; ++c2) {
                    int cc = half * 2 + c2;
                    int ch = w * 64 + cc * 16 + l15;
                    f32x4 part = *(const f32x4*)&mrgO[w * 32 + c2 * 16 + l15][qb];
                    size_t off = ((size_t)(b * NC + ch)) * NSP + m0 + qb;
                    float4 e = *(const float4*)(ef + off);
                    float4 o;
                    o.x = (acc[qc2][cc][0] + part[0]) * r0 + e.x;
                    o.y = (acc[qc2][cc][1] + part[1]) * r1 + e.y;
                    o.z = (acc[qc2][cc][2] + part[2]) * r2 + e.z;
                    o.w = (acc[qc2][cc][3] + part[3]) * r3 + e.w;
                    *(float4*)(out + off) = o;
                }
            }
        }
        __syncthreads();   // protect mrgO before next half's writes
    }
}

// ---------------------------------------------------------------------------
extern "C" void kernel_launch(void* const* d_in, const int* in_sizes, int n_in,
                              void* d_out, int out_size, void* d_ws, size_t ws_size,
                              hipStream_t stream) {
    const float* ef    = (const float*)d_in[0];
    const float* sf    = (const float*)d_in[1];
    const float* attn  = (const float*)d_in[2];
    const float* Qw    = (const float*)d_in[3];
    const float* Qb    = (const float*)d_in[4];
    const float* Kw    = (const float*)d_in[5];
    const float* Kb    = (const float*)d_in[6];
    const float* Vw    = (const float*)d_in[7];
    const float* Vb    = (const float*)d_in[8];
    const float* gamma = (const float*)d_in[9];
    float* out = (float*)d_out;

    // workspace carve (~10.8 MB)
    unsigned short* qws  = (unsigned short*)d_ws;                    // 4*4096*32
    unsigned short* kws  = qws + (size_t)4 * 4096 * 32;              // 4*4096*32
    unsigned short* vws  = kws + (size_t)4 * 4096 * 32;              // 4*128*256*32
    unsigned short* Qwbf = vws + (size_t)4 * 128 * 256 * 32;         // 32*512
    unsigned short* Kwbf = Qwbf + 32 * 512;                          // 32*256
    unsigned short* Vwbf = Kwbf + 32 * 256;                          // 256*512

    hipLaunchKernelGGL(prep_w, dim3(64), dim3(256), 0, stream,
                       Qw, Kw, Vw, Qwbf, Kwbf, Vwbf);
    hipLaunchKernelGGL(proj_fused, dim3(256, 4), dim3(256), 0, stream,
                       ef, sf, attn, Qwbf, Qb, Kwbf, Kb, Vwbf, Vb, qws, kws, vws);
    hipLaunchKernelGGL(attention, dim3(512), dim3(512), 0, stream,
                       qws, kws, vws, ef, gamma, out);
}

// Round 4
// 178.573 us; speedup vs baseline: 1.6849x; 1.6849x over previous
//
#include <hip/hip_runtime.h>
#include <hip/hip_bf16.h>

typedef short bf16x8 __attribute__((ext_vector_type(8)));
typedef float f32x4 __attribute__((ext_vector_type(4)));

#define MFMA16(a, b, c) __builtin_amdgcn_mfma_f32_16x16x32_bf16(a, b, c, 0, 0, 0)

#define NB 4
#define NC 256
#define NSP 4096
#define LOG2E 1.4426950408889634f

__device__ __forceinline__ unsigned short f2bf(float f) {
    return (unsigned short)((__float_as_uint(f) + 0x8000u) >> 16);
}
// packed pair: (bf(hi)<<16)|bf(lo) via v_perm_b32 — 3 VALU ops
__device__ __forceinline__ unsigned pk2bf(float hi, float lo) {
    return __builtin_amdgcn_perm(__float_as_uint(hi) + 0x8000u,
                                 __float_as_uint(lo) + 0x8000u, 0x07060302u);
}

// ---------------------------------------------------------------------------
// prep_w: weights -> bf16, natural [o][ci] layout. (proven verbatim)
// ---------------------------------------------------------------------------
__global__ __launch_bounds__(256) void prep_w(
    const float* __restrict__ Qw, const float* __restrict__ Kw,
    const float* __restrict__ Vw,
    unsigned short* __restrict__ Qwbf, unsigned short* __restrict__ Kwbf,
    unsigned short* __restrict__ Vwbf)
{
    int i = blockIdx.x * 256 + threadIdx.x;   // 0..16383
    {
        const float4* vs = (const float4*)(Vw + (size_t)i * 8);
        float4 a = vs[0], c = vs[1];
        int4 st;
        st.x = (int)pk2bf(a.y, a.x); st.y = (int)pk2bf(a.w, a.z);
        st.z = (int)pk2bf(c.y, c.x); st.w = (int)pk2bf(c.w, c.z);
        *(int4*)(Vwbf + (size_t)i * 8) = st;
    }
    if (i < 2048) {
        const float4* qs = (const float4*)(Qw + (size_t)i * 8);
        float4 a = qs[0], c = qs[1];
        int4 st;
        st.x = (int)pk2bf(a.y, a.x); st.y = (int)pk2bf(a.w, a.z);
        st.z = (int)pk2bf(c.y, c.x); st.w = (int)pk2bf(c.w, c.z);
        *(int4*)(Qwbf + (size_t)i * 8) = st;
    }
    if (i < 1024) {
        const float4* ks = (const float4*)(Kw + (size_t)i * 8);
        float4 a = ks[0], c = ks[1];
        int4 st;
        st.x = (int)pk2bf(a.y, a.x); st.y = (int)pk2bf(a.w, a.z);
        st.z = (int)pk2bf(c.y, c.x); st.w = (int)pk2bf(c.w, c.z);
        *(int4*)(Kwbf + (size_t)i * 8) = st;
    }
}

// ---------------------------------------------------------------------------
// proj_qv: FUSED Q+V projection (R1-proven, separate launch — R2/R3 showed
// role-fused single launches are 19-37us WORSE than separate launches).
// Register-pipelined staging; Q adds 2 MFMAs/chunk reusing V's A-fragments.
// ---------------------------------------------------------------------------
__global__ __launch_bounds__(256) void proj_qv(
    const float* __restrict__ ef, const float* __restrict__ sf,
    const unsigned short* __restrict__ Qwbf, const float* __restrict__ Qb,
    const unsigned short* __restrict__ Vwbf, const float* __restrict__ Vb,
    unsigned short* __restrict__ qws, unsigned short* __restrict__ vws)
{
    __shared__ __align__(16) unsigned short xt[32][72];

    int t = threadIdx.x;
    int w = t >> 6, lane = t & 63, quad = lane >> 4, l15 = lane & 15;
    int mt = blockIdx.x, b = blockIdx.y, m0 = mt * 32;
    int ci = t & 63, sm = t >> 6;
    int mi = w >> 1, oh = w & 1;

    f32x4 zero = {0.f, 0.f, 0.f, 0.f};
    f32x4 acc[2][4];
#pragma unroll
    for (int m = 0; m < 2; ++m)
#pragma unroll
        for (int ot = 0; ot < 4; ++ot) acc[m][ot] = zero;
    f32x4 qacc = zero;

    // preload chunk 0
    const float* s0p = ef + ((size_t)(b * NC) + ci) * NSP + m0 + sm * 8;
    float4 x0 = *(const float4*)s0p;
    float4 x1 = *(const float4*)(s0p + 4);

    for (int c = 0; c < 8; ++c) {
        float4 n0 = x0, n1 = x1;
        if (c < 7) {
            int cn = c + 1;
            const float* sn = (cn < 4 ? ef : sf) +
                              ((size_t)(b * NC) + (cn & 3) * 64 + ci) * NSP + m0 + sm * 8;
            n0 = *(const float4*)sn;
            n1 = *(const float4*)(sn + 4);
        }
        __syncthreads();   // protect previous chunk's LDS reads
        unsigned short* xd = &xt[sm * 8][ci];
        xd[0]   = f2bf(x0.x); xd[72]  = f2bf(x0.y);
        xd[144] = f2bf(x0.z); xd[216] = f2bf(x0.w);
        xd[288] = f2bf(x1.x); xd[360] = f2bf(x1.y);
        xd[432] = f2bf(x1.z); xd[504] = f2bf(x1.w);
        __syncthreads();
        int ci0 = c * 64;
#pragma unroll
        for (int ks = 0; ks < 2; ++ks) {
            bf16x8 a0 = *(const bf16x8*)&xt[l15][ks * 32 + quad * 8];
            bf16x8 a1 = *(const bf16x8*)&xt[16 + l15][ks * 32 + quad * 8];
            bf16x8 bq = *(const bf16x8*)(Qwbf + (size_t)(oh * 16 + l15) * 512 + ci0 + ks * 32 + quad * 8);
            qacc = MFMA16(mi ? a1 : a0, bq, qacc);
#pragma unroll
            for (int ot = 0; ot < 4; ++ot) {
                bf16x8 bv = *(const bf16x8*)(Vwbf + (size_t)(w * 64 + ot * 16 + l15) * 512 + ci0 + ks * 32 + quad * 8);
                acc[0][ot] = MFMA16(a0, bv, acc[0][ot]);
                acc[1][ot] = MFMA16(a1, bv, acc[1][ot]);
            }
        }
        x0 = n0; x1 = n1;
    }

    // V epilogue
#pragma unroll
    for (int ot = 0; ot < 4; ++ot) {
        int ch = w * 64 + ot * 16 + l15;
        float bias = Vb[ch];
        unsigned* vp = (unsigned*)(vws + ((size_t)((b * 128 + mt) * 256 + ch)) * 32);
#pragma unroll
        for (int r = 0; r < 4; ++r)
            vp[quad * 4 + r] = pk2bf(acc[1][ot][r] + bias, acc[0][ot][r] + bias);
    }

    // Q epilogue
    {
        int o = oh * 16 + l15;
        float bb = Qb[o];
#pragma unroll
        for (int r = 0; r < 4; ++r) {
            int m = m0 + mi * 16 + quad * 4 + r;
            qws[((size_t)(b * NSP) + m) * 32 + o] = f2bf((qacc[r] + bb) * LOG2E);
        }
    }
}

// ---------------------------------------------------------------------------
// proj_k: R1-proven, register-pipelined (4 chunks, Kwbf 256-wide).
// ---------------------------------------------------------------------------
__global__ __launch_bounds__(256) void proj_k(
    const float* __restrict__ attn,
    const unsigned short* __restrict__ Kwbf, const float* __restrict__ Kb,
    unsigned short* __restrict__ kws)
{
    __shared__ __align__(16) unsigned short xt[32][72];

    int t = threadIdx.x;
    int w = t >> 6, lane = t & 63, quad = lane >> 4, l15 = lane & 15;
    int mt = blockIdx.x, b = blockIdx.y, m0 = mt * 32;
    int ci = t & 63, sm = t >> 6;
    int mi = w >> 1, oh = w & 1;

    f32x4 acc = {0.f, 0.f, 0.f, 0.f};

    const float* s0p = attn + ((size_t)(b * NC) + ci) * NSP + m0 + sm * 8;
    float4 x0 = *(const float4*)s0p;
    float4 x1 = *(const float4*)(s0p + 4);

    for (int c = 0; c < 4; ++c) {
        float4 n0 = x0, n1 = x1;
        if (c < 3) {
            const float* sn = attn + ((size_t)(b * NC) + (c + 1) * 64 + ci) * NSP + m0 + sm * 8;
            n0 = *(const float4*)sn;
            n1 = *(const float4*)(sn + 4);
        }
        __syncthreads();
        unsigned short* xd = &xt[sm * 8][ci];
        xd[0]   = f2bf(x0.x); xd[72]  = f2bf(x0.y);
        xd[144] = f2bf(x0.z); xd[216] = f2bf(x0.w);
        xd[288] = f2bf(x1.x); xd[360] = f2bf(x1.y);
        xd[432] = f2bf(x1.z); xd[504] = f2bf(x1.w);
        __syncthreads();
        int ci0 = c * 64;
#pragma unroll
        for (int ks = 0; ks < 2; ++ks) {
            bf16x8 a  = *(const bf16x8*)&xt[mi * 16 + l15][ks * 32 + quad * 8];
            bf16x8 bk = *(const bf16x8*)(Kwbf + (size_t)(oh * 16 + l15) * 256 + ci0 + ks * 32 + quad * 8);
            acc = MFMA16(a, bk, acc);
        }
        x0 = n0; x1 = n1;
    }

    int o = oh * 16 + l15;
    float bb = Kb[o];
#pragma unroll
    for (int r = 0; r < 4; ++r) {
        int m = m0 + mi * 16 + quad * 4 + r;
        kws[((size_t)(b * NSP) + m) * 32 + o] = f2bf(acc[r] + bb);
    }
}

// ---------------------------------------------------------------------------
// attention: R0's proven 60.6us structure VERBATIM (512 thr, 64 q/block,
// 107KB LDS, launch_bounds(512,2), mrg-buffer merge, NO setprio), with ONE
// change: 2x loop unroll with ping-pong V buffers (vfA/vfB), eliminating the
// 32 v_mov vfn->vf copies per iteration. Peak register liveness unchanged
// (both buffers were already live across the barrier).
// ---------------------------------------------------------------------------

// One attention iteration: QK on kf -> exp -> P store -> prefetch (kf, VNXT)
// -> barrier -> PV with VCUR.
#define ATT_ITER(IT, VCUR, VNXT)                                              \
    {                                                                         \
        int buf = (IT) & 1;                                                   \
        f32x4 s0 = MFMA16(qf, kf[0], zero);                                   \
        f32x4 s1 = MFMA16(qf, kf[1], zero);                                   \
        f32x4 s2 = MFMA16(qf, kf[2], zero);                                   \
        f32x4 s3 = MFMA16(qf, kf[3], zero);                                   \
        float e0[4], e1[4], e2[4], e3[4];                                     \
        _Pragma("unroll")                                                     \
        for (int r = 0; r < 4; ++r) {                                         \
            e0[r] = __builtin_amdgcn_exp2f(s0[r]);                            \
            e1[r] = __builtin_amdgcn_exp2f(s1[r]);                            \
            e2[r] = __builtin_amdgcn_exp2f(s2[r]);                            \
            e3[r] = __builtin_amdgcn_exp2f(s3[r]);                            \
        }                                                                     \
        lp0 += (e0[0] + e1[0]) + (e2[0] + e3[0]);                             \
        lp1 += (e0[1] + e1[1]) + (e2[1] + e3[1]);                             \
        lp2 += (e0[2] + e1[2]) + (e2[2] + e3[2]);                             \
        lp3 += (e0[3] + e1[3]) + (e2[3] + e3[3]);                             \
        unsigned short* pd = &Plds[g][buf][(w * 16 + quad * 4) * 72 + 2 * l15]; \
        _Pragma("unroll")                                                     \
        for (int r = 0; r < 4; ++r) {                                         \
            *(unsigned*)(pd + r * 72)      = pk2bf(e1[r], e0[r]);             \
            *(unsigned*)(pd + r * 72 + 32) = pk2bf(e3[r], e2[r]);             \
        }                                                                     \
        int itn = (IT) + 1 < 32 ? (IT) + 1 : 31;                              \
        int ttn = tt0 + 2 * itn;                                              \
        _Pragma("unroll")                                                     \
        for (int j = 0; j < 4; ++j)                                           \
            kf[j] = *(const bf16x8*)(kbase + (size_t)((ttn + (j >> 1)) * 32 + (j & 1) * 16 + l15) * 32 + quad * 8); \
        _Pragma("unroll")                                                     \
        for (int h = 0; h < 2; ++h)                                           \
            _Pragma("unroll")                                                 \
            for (int cc = 0; cc < 4; ++cc)                                    \
                VNXT[h][cc] = *(const bf16x8*)(vbase + (size_t)(ttn + h) * 8192 + (w * 64 + cc * 16 + l15) * 32 + quad * 8); \
        __syncthreads();                                                      \
        _Pragma("unroll")                                                     \
        for (int h = 0; h < 2; ++h) {                                         \
            bf16x8 pa0 = *(const bf16x8*)&Plds[g][buf][(0  + l15) * 72 + h * 32 + quad * 8]; \
            bf16x8 pa1 = *(const bf16x8*)&Plds[g][buf][(16 + l15) * 72 + h * 32 + quad * 8]; \
            bf16x8 pa2 = *(const bf16x8*)&Plds[g][buf][(32 + l15) * 72 + h * 32 + quad * 8]; \
            bf16x8 pa3 = *(const bf16x8*)&Plds[g][buf][(48 + l15) * 72 + h * 32 + quad * 8]; \
            _Pragma("unroll")                                                 \
            for (int cc = 0; cc < 4; ++cc) {                                  \
                acc[0][cc] = MFMA16(pa0, VCUR[h][cc], acc[0][cc]);            \
                acc[1][cc] = MFMA16(pa1, VCUR[h][cc], acc[1][cc]);            \
                acc[2][cc] = MFMA16(pa2, VCUR[h][cc], acc[2][cc]);            \
                acc[3][cc] = MFMA16(pa3, VCUR[h][cc], acc[3][cc]);            \
            }                                                                 \
        }                                                                     \
    }

__global__ __launch_bounds__(512, 2) void attention(
    const unsigned short* __restrict__ qws, const unsigned short* __restrict__ kws,
    const unsigned short* __restrict__ vws, const float* __restrict__ ef,
    const float* __restrict__ gamma, float* __restrict__ out)
{
    __shared__ unsigned short Plds[2][2][64 * 72];   // [g][buf][q][72]
    __shared__ float mrg[256][68];
    __shared__ float denl[2][64];

    int t = threadIdx.x;
    int g = t >> 8, tl = t & 255;
    int w = tl >> 6, lane = tl & 63, quad = lane >> 4, l15 = lane & 15;
    int b = blockIdx.x >> 6, m0 = (blockIdx.x & 63) << 6;

    const unsigned short* kbase = kws + (size_t)(b * NSP) * 32;
    const unsigned short* vbase = vws + (size_t)(b * 128) * 8192;

    bf16x8 qf = *(const bf16x8*)(qws + ((size_t)(b * NSP) + m0 + w * 16 + l15) * 32 + quad * 8);

    f32x4 zero = {0.f, 0.f, 0.f, 0.f};
    f32x4 acc[4][4];
#pragma unroll
    for (int i = 0; i < 4; ++i)
#pragma unroll
        for (int j = 0; j < 4; ++j) acc[i][j] = zero;
    float lp0 = 0.f, lp1 = 0.f, lp2 = 0.f, lp3 = 0.f;

    int tt0 = g * 64;   // first 32-key tile of this group
    bf16x8 kf[4];
#pragma unroll
    for (int j = 0; j < 4; ++j)
        kf[j] = *(const bf16x8*)(kbase + (size_t)((tt0 + (j >> 1)) * 32 + (j & 1) * 16 + l15) * 32 + quad * 8);
    bf16x8 vfA[2][4], vfB[2][4];
#pragma unroll
    for (int h = 0; h < 2; ++h)
#pragma unroll
        for (int cc = 0; cc < 4; ++cc)
            vfA[h][cc] = *(const bf16x8*)(vbase + (size_t)(tt0 + h) * 8192 + (w * 64 + cc * 16 + l15) * 32 + quad * 8);

    for (int it2 = 0; it2 < 16; ++it2) {
        ATT_ITER(2 * it2,     vfA, vfB);
        ATT_ITER(2 * it2 + 1, vfB, vfA);
    }

    // per-group denominator partials
    lp0 += __shfl_xor(lp0, 1); lp0 += __shfl_xor(lp0, 2); lp0 += __shfl_xor(lp0, 4); lp0 += __shfl_xor(lp0, 8);
    lp1 += __shfl_xor(lp1, 1); lp1 += __shfl_xor(lp1, 2); lp1 += __shfl_xor(lp1, 4); lp1 += __shfl_xor(lp1, 8);
    lp2 += __shfl_xor(lp2, 1); lp2 += __shfl_xor(lp2, 2); lp2 += __shfl_xor(lp2, 4); lp2 += __shfl_xor(lp2, 8);
    lp3 += __shfl_xor(lp3, 1); lp3 += __shfl_xor(lp3, 2); lp3 += __shfl_xor(lp3, 4); lp3 += __shfl_xor(lp3, 8);
    if (l15 == 0) {
        int base = w * 16 + quad * 4;
        denl[g][base + 0] = lp0; denl[g][base + 1] = lp1;
        denl[g][base + 2] = lp2; denl[g][base + 3] = lp3;
    }
    if (g == 1) {
#pragma unroll
        for (int qc = 0; qc < 4; ++qc)
#pragma unroll
            for (int cc = 0; cc < 4; ++cc)
                *(f32x4*)&mrg[w * 64 + cc * 16 + l15][qc * 16 + quad * 4] = acc[qc][cc];
    }
    __syncthreads();

    if (g == 0) {
        float gam = gamma[0];
#pragma unroll
        for (int qc = 0; qc < 4; ++qc) {
            int qb = qc * 16 + quad * 4;
            float4 d0 = *(const float4*)&denl[0][qb];
            float4 d1 = *(const float4*)&denl[1][qb];
            float r0 = gam / (d0.x + d1.x), r1 = gam / (d0.y + d1.y);
            float r2 = gam / (d0.z + d1.z), r3 = gam / (d0.w + d1.w);
#pragma unroll
            for (int cc = 0; cc < 4; ++cc) {
                int ch = w * 64 + cc * 16 + l15;
                f32x4 part = *(const f32x4*)&mrg[ch][qb];
                size_t off = ((size_t)(b * NC + ch)) * NSP + m0 + qb;
                float4 e = *(const float4*)(ef + off);
                float4 o;
                o.x = (acc[qc][cc][0] + part[0]) * r0 + e.x;
                o.y = (acc[qc][cc][1] + part[1]) * r1 + e.y;
                o.z = (acc[qc][cc][2] + part[2]) * r2 + e.z;
                o.w = (acc[qc][cc][3] + part[3]) * r3 + e.w;
                *(float4*)(out + off) = o;
            }
        }
    }
}

// ---------------------------------------------------------------------------
extern "C" void kernel_launch(void* const* d_in, const int* in_sizes, int n_in,
                              void* d_out, int out_size, void* d_ws, size_t ws_size,
                              hipStream_t stream) {
    const float* ef    = (const float*)d_in[0];
    const float* sf    = (const float*)d_in[1];
    const float* attn  = (const float*)d_in[2];
    const float* Qw    = (const float*)d_in[3];
    const float* Qb    = (const float*)d_in[4];
    const float* Kw    = (const float*)d_in[5];
    const float* Kb    = (const float*)d_in[6];
    const float* Vw    = (const float*)d_in[7];
    const float* Vb    = (const float*)d_in[8];
    const float* gamma = (const float*)d_in[9];
    float* out = (float*)d_out;

    // workspace carve (~10.8 MB)
    unsigned short* qws  = (unsigned short*)d_ws;                    // 4*4096*32
    unsigned short* kws  = qws + (size_t)4 * 4096 * 32;              // 4*4096*32
    unsigned short* vws  = kws + (size_t)4 * 4096 * 32;              // 4*128*256*32
    unsigned short* Qwbf = vws + (size_t)4 * 128 * 256 * 32;         // 32*512
    unsigned short* Kwbf = Qwbf + 32 * 512;                          // 32*256
    unsigned short* Vwbf = Kwbf + 32 * 256;                          // 256*512

    hipLaunchKernelGGL(prep_w, dim3(64), dim3(256), 0, stream,
                       Qw, Kw, Vw, Qwbf, Kwbf, Vwbf);
    hipLaunchKernelGGL(proj_qv, dim3(128, 4), dim3(256), 0, stream,
                       ef, sf, Qwbf, Qb, Vwbf, Vb, qws, vws);
    hipLaunchKernelGGL(proj_k, dim3(128, 4), dim3(256), 0, stream,
                       attn, Kwbf, Kb, kws);
    hipLaunchKernelGGL(attention, dim3(256), dim3(512), 0, stream,
                       qws, kws, vws, ef, gamma, out);
}

// Round 5
// 174.461 us; speedup vs baseline: 1.7246x; 1.0236x over previous
//
#include <hip/hip_runtime.h>
#include <hip/hip_bf16.h>

typedef short bf16x8 __attribute__((ext_vector_type(8)));
typedef float f32x4 __attribute__((ext_vector_type(4)));

#define MFMA16(a, b, c) __builtin_amdgcn_mfma_f32_16x16x32_bf16(a, b, c, 0, 0, 0)

#define NB 4
#define NC 256
#define NSP 4096
#define LOG2E 1.4426950408889634f

__device__ __forceinline__ unsigned short f2bf(float f) {
    return (unsigned short)((__float_as_uint(f) + 0x8000u) >> 16);
}
// packed pair: (bf(hi)<<16)|bf(lo) via v_perm_b32 — 3 VALU ops
__device__ __forceinline__ unsigned pk2bf(float hi, float lo) {
    return __builtin_amdgcn_perm(__float_as_uint(hi) + 0x8000u,
                                 __float_as_uint(lo) + 0x8000u, 0x07060302u);
}

// ---------------------------------------------------------------------------
// prep_w: weights -> bf16, natural [o][ci] layout. (proven verbatim)
// ---------------------------------------------------------------------------
__global__ __launch_bounds__(256) void prep_w(
    const float* __restrict__ Qw, const float* __restrict__ Kw,
    const float* __restrict__ Vw,
    unsigned short* __restrict__ Qwbf, unsigned short* __restrict__ Kwbf,
    unsigned short* __restrict__ Vwbf)
{
    int i = blockIdx.x * 256 + threadIdx.x;   // 0..16383
    {
        const float4* vs = (const float4*)(Vw + (size_t)i * 8);
        float4 a = vs[0], c = vs[1];
        int4 st;
        st.x = (int)pk2bf(a.y, a.x); st.y = (int)pk2bf(a.w, a.z);
        st.z = (int)pk2bf(c.y, c.x); st.w = (int)pk2bf(c.w, c.z);
        *(int4*)(Vwbf + (size_t)i * 8) = st;
    }
    if (i < 2048) {
        const float4* qs = (const float4*)(Qw + (size_t)i * 8);
        float4 a = qs[0], c = qs[1];
        int4 st;
        st.x = (int)pk2bf(a.y, a.x); st.y = (int)pk2bf(a.w, a.z);
        st.z = (int)pk2bf(c.y, c.x); st.w = (int)pk2bf(c.w, c.z);
        *(int4*)(Qwbf + (size_t)i * 8) = st;
    }
    if (i < 1024) {
        const float4* ks = (const float4*)(Kw + (size_t)i * 8);
        float4 a = ks[0], c = ks[1];
        int4 st;
        st.x = (int)pk2bf(a.y, a.x); st.y = (int)pk2bf(a.w, a.z);
        st.z = (int)pk2bf(c.y, c.x); st.w = (int)pk2bf(c.w, c.z);
        *(int4*)(Kwbf + (size_t)i * 8) = st;
    }
}

// ---------------------------------------------------------------------------
// proj_qv: fused Q+V projection, separate launch (R2/R3: role-fusion loses).
// NEW: COALESCED staging. Old: lane=ci -> 64 lanes stride 16KB (64 scattered
// 32B segments/wave). New: u=t&7 (m-quad), v=t>>3 (row pair 2v,2v+1) -> each
// wave reads 8 contiguous 128B segments/pass; LDS write is 4 packed dword
// writes (ci-pair) instead of 8 b16 writes. MFMA phase unchanged.
// ---------------------------------------------------------------------------
__global__ __launch_bounds__(256) void proj_qv(
    const float* __restrict__ ef, const float* __restrict__ sf,
    const unsigned short* __restrict__ Qwbf, const float* __restrict__ Qb,
    const unsigned short* __restrict__ Vwbf, const float* __restrict__ Vb,
    unsigned short* __restrict__ qws, unsigned short* __restrict__ vws)
{
    __shared__ __align__(16) unsigned short xt[32][72];

    int t = threadIdx.x;
    int w = t >> 6, lane = t & 63, quad = lane >> 4, l15 = lane & 15;
    int mt = blockIdx.x, b = blockIdx.y, m0 = mt * 32;
    int u = t & 7, v = t >> 3;          // m_off = u*4, rows 2v, 2v+1
    int mi = w >> 1, oh = w & 1;

    f32x4 zero = {0.f, 0.f, 0.f, 0.f};
    f32x4 acc[2][4];
#pragma unroll
    for (int m = 0; m < 2; ++m)
#pragma unroll
        for (int ot = 0; ot < 4; ++ot) acc[m][ot] = zero;
    f32x4 qacc = zero;

    // preload chunk 0 (rows 2v, 2v+1 of ef)
    const float* s0p = ef + ((size_t)(b * NC) + 2 * v) * NSP + m0 + u * 4;
    float4 xA = *(const float4*)s0p;
    float4 xB = *(const float4*)(s0p + NSP);

    for (int c = 0; c < 8; ++c) {
        float4 nA = xA, nB = xB;
        if (c < 7) {
            int cn = c + 1;
            const float* sn = (cn < 4 ? ef : sf) +
                              ((size_t)(b * NC) + (cn & 3) * 64 + 2 * v) * NSP + m0 + u * 4;
            nA = *(const float4*)sn;
            nB = *(const float4*)(sn + NSP);
        }
        __syncthreads();   // protect previous chunk's LDS reads
        unsigned* xw = (unsigned*)&xt[u * 4][2 * v];   // row stride = 36 dwords
        xw[0]   = pk2bf(xB.x, xA.x);
        xw[36]  = pk2bf(xB.y, xA.y);
        xw[72]  = pk2bf(xB.z, xA.z);
        xw[108] = pk2bf(xB.w, xA.w);
        __syncthreads();
        int ci0 = c * 64;
#pragma unroll
        for (int ks = 0; ks < 2; ++ks) {
            bf16x8 a0 = *(const bf16x8*)&xt[l15][ks * 32 + quad * 8];
            bf16x8 a1 = *(const bf16x8*)&xt[16 + l15][ks * 32 + quad * 8];
            bf16x8 bq = *(const bf16x8*)(Qwbf + (size_t)(oh * 16 + l15) * 512 + ci0 + ks * 32 + quad * 8);
            qacc = MFMA16(mi ? a1 : a0, bq, qacc);
#pragma unroll
            for (int ot = 0; ot < 4; ++ot) {
                bf16x8 bv = *(const bf16x8*)(Vwbf + (size_t)(w * 64 + ot * 16 + l15) * 512 + ci0 + ks * 32 + quad * 8);
                acc[0][ot] = MFMA16(a0, bv, acc[0][ot]);
                acc[1][ot] = MFMA16(a1, bv, acc[1][ot]);
            }
        }
        xA = nA; xB = nB;
    }

    // V epilogue
#pragma unroll
    for (int ot = 0; ot < 4; ++ot) {
        int ch = w * 64 + ot * 16 + l15;
        float bias = Vb[ch];
        unsigned* vp = (unsigned*)(vws + ((size_t)((b * 128 + mt) * 256 + ch)) * 32);
#pragma unroll
        for (int r = 0; r < 4; ++r)
            vp[quad * 4 + r] = pk2bf(acc[1][ot][r] + bias, acc[0][ot][r] + bias);
    }

    // Q epilogue
    {
        int o = oh * 16 + l15;
        float bb = Qb[o];
#pragma unroll
        for (int r = 0; r < 4; ++r) {
            int m = m0 + mi * 16 + quad * 4 + r;
            qws[((size_t)(b * NSP) + m) * 32 + o] = f2bf((qacc[r] + bb) * LOG2E);
        }
    }
}

// ---------------------------------------------------------------------------
// proj_k: same coalesced staging (4 chunks, Kwbf 256-wide).
// ---------------------------------------------------------------------------
__global__ __launch_bounds__(256) void proj_k(
    const float* __restrict__ attn,
    const unsigned short* __restrict__ Kwbf, const float* __restrict__ Kb,
    unsigned short* __restrict__ kws)
{
    __shared__ __align__(16) unsigned short xt[32][72];

    int t = threadIdx.x;
    int w = t >> 6, lane = t & 63, quad = lane >> 4, l15 = lane & 15;
    int mt = blockIdx.x, b = blockIdx.y, m0 = mt * 32;
    int u = t & 7, v = t >> 3;
    int mi = w >> 1, oh = w & 1;

    f32x4 acc = {0.f, 0.f, 0.f, 0.f};

    const float* s0p = attn + ((size_t)(b * NC) + 2 * v) * NSP + m0 + u * 4;
    float4 xA = *(const float4*)s0p;
    float4 xB = *(const float4*)(s0p + NSP);

    for (int c = 0; c < 4; ++c) {
        float4 nA = xA, nB = xB;
        if (c < 3) {
            const float* sn = attn + ((size_t)(b * NC) + (c + 1) * 64 + 2 * v) * NSP + m0 + u * 4;
            nA = *(const float4*)sn;
            nB = *(const float4*)(sn + NSP);
        }
        __syncthreads();
        unsigned* xw = (unsigned*)&xt[u * 4][2 * v];
        xw[0]   = pk2bf(xB.x, xA.x);
        xw[36]  = pk2bf(xB.y, xA.y);
        xw[72]  = pk2bf(xB.z, xA.z);
        xw[108] = pk2bf(xB.w, xA.w);
        __syncthreads();
        int ci0 = c * 64;
#pragma unroll
        for (int ks = 0; ks < 2; ++ks) {
            bf16x8 a  = *(const bf16x8*)&xt[mi * 16 + l15][ks * 32 + quad * 8];
            bf16x8 bk = *(const bf16x8*)(Kwbf + (size_t)(oh * 16 + l15) * 256 + ci0 + ks * 32 + quad * 8);
            acc = MFMA16(a, bk, acc);
        }
        xA = nA; xB = nB;
    }

    int o = oh * 16 + l15;
    float bb = Kb[o];
#pragma unroll
    for (int r = 0; r < 4; ++r) {
        int m = m0 + mi * 16 + quad * 4 + r;
        kws[((size_t)(b * NSP) + m) * 32 + o] = f2bf(acc[r] + bb);
    }
}

// ---------------------------------------------------------------------------
// attention: R4 structure (512 thr, 64 q/block, 107KB LDS, ping-pong V,
// no setprio) + SOFTWARE PIPELINE: after the barrier of iter IT, PV(IT)
// runs in parallel with QK(IT+1)+exp+P-store (independent: PV reads buf,
// new P goes to buf^1). Prologue computes P(0); last iter skips QK phase.
// One barrier per iteration, same math, same buffers.
// ---------------------------------------------------------------------------
#define ATT_PIPE(IT, VCUR, VNXT, DONEXT)                                      \
    {                                                                         \
        int buf = (IT) & 1;                                                   \
        __syncthreads();   /* P(IT) visible; buf^1 reads (iter IT-1) done */  \
        f32x4 s0, s1, s2, s3;                                                 \
        if (DONEXT) {                                                         \
            s0 = MFMA16(qf, kf[0], zero);                                     \
            s1 = MFMA16(qf, kf[1], zero);                                     \
            s2 = MFMA16(qf, kf[2], zero);                                     \
            s3 = MFMA16(qf, kf[3], zero);                                     \
        }                                                                     \
        if (DONEXT) {                                                         \
            int tk = (IT) + 2 < 32 ? (IT) + 2 : 31;                           \
            int tv = (IT) + 1 < 32 ? (IT) + 1 : 31;                           \
            int ttk = tt0 + 2 * tk, ttv = tt0 + 2 * tv;                       \
            _Pragma("unroll")                                                 \
            for (int j = 0; j < 4; ++j)                                       \
                kf[j] = *(const bf16x8*)(kbase + (size_t)((ttk + (j >> 1)) * 32 + (j & 1) * 16 + l15) * 32 + quad * 8); \
            _Pragma("unroll")                                                 \
            for (int h = 0; h < 2; ++h)                                       \
                _Pragma("unroll")                                             \
                for (int cc = 0; cc < 4; ++cc)                                \
                    VNXT[h][cc] = *(const bf16x8*)(vbase + (size_t)(ttv + h) * 8192 + (w * 64 + cc * 16 + l15) * 32 + quad * 8); \
        }                                                                     \
        _Pragma("unroll")                                                     \
        for (int h = 0; h < 2; ++h) {                                         \
            bf16x8 pa0 = *(const bf16x8*)&Plds[g][buf][(0  + l15) * 72 + h * 32 + quad * 8]; \
            bf16x8 pa1 = *(const bf16x8*)&Plds[g][buf][(16 + l15) * 72 + h * 32 + quad * 8]; \
            bf16x8 pa2 = *(const bf16x8*)&Plds[g][buf][(32 + l15) * 72 + h * 32 + quad * 8]; \
            bf16x8 pa3 = *(const bf16x8*)&Plds[g][buf][(48 + l15) * 72 + h * 32 + quad * 8]; \
            _Pragma("unroll")                                                 \
            for (int cc = 0; cc < 4; ++cc) {                                  \
                acc[0][cc] = MFMA16(pa0, VCUR[h][cc], acc[0][cc]);            \
                acc[1][cc] = MFMA16(pa1, VCUR[h][cc], acc[1][cc]);            \
                acc[2][cc] = MFMA16(pa2, VCUR[h][cc], acc[2][cc]);            \
                acc[3][cc] = MFMA16(pa3, VCUR[h][cc], acc[3][cc]);            \
            }                                                                 \
        }                                                                     \
        if (DONEXT) {                                                         \
            float e0[4], e1[4], e2[4], e3[4];                                 \
            _Pragma("unroll")                                                 \
            for (int r = 0; r < 4; ++r) {                                     \
                e0[r] = __builtin_amdgcn_exp2f(s0[r]);                        \
                e1[r] = __builtin_amdgcn_exp2f(s1[r]);                        \
                e2[r] = __builtin_amdgcn_exp2f(s2[r]);                        \
                e3[r] = __builtin_amdgcn_exp2f(s3[r]);                        \
            }                                                                 \
            lp0 += (e0[0] + e1[0]) + (e2[0] + e3[0]);                         \
            lp1 += (e0[1] + e1[1]) + (e2[1] + e3[1]);                         \
            lp2 += (e0[2] + e1[2]) + (e2[2] + e3[2]);                         \
            lp3 += (e0[3] + e1[3]) + (e2[3] + e3[3]);                         \
            unsigned short* pd = &Plds[g][buf ^ 1][(w * 16 + quad * 4) * 72 + 2 * l15]; \
            _Pragma("unroll")                                                 \
            for (int r = 0; r < 4; ++r) {                                     \
                *(unsigned*)(pd + r * 72)      = pk2bf(e1[r], e0[r]);         \
                *(unsigned*)(pd + r * 72 + 32) = pk2bf(e3[r], e2[r]);         \
            }                                                                 \
        }                                                                     \
    }

__global__ __launch_bounds__(512, 2) void attention(
    const unsigned short* __restrict__ qws, const unsigned short* __restrict__ kws,
    const unsigned short* __restrict__ vws, const float* __restrict__ ef,
    const float* __restrict__ gamma, float* __restrict__ out)
{
    __shared__ unsigned short Plds[2][2][64 * 72];   // [g][buf][q][72]
    __shared__ float mrg[256][68];
    __shared__ float denl[2][64];

    int t = threadIdx.x;
    int g = t >> 8, tl = t & 255;
    int w = tl >> 6, lane = tl & 63, quad = lane >> 4, l15 = lane & 15;
    int b = blockIdx.x >> 6, m0 = (blockIdx.x & 63) << 6;

    const unsigned short* kbase = kws + (size_t)(b * NSP) * 32;
    const unsigned short* vbase = vws + (size_t)(b * 128) * 8192;

    bf16x8 qf = *(const bf16x8*)(qws + ((size_t)(b * NSP) + m0 + w * 16 + l15) * 32 + quad * 8);

    f32x4 zero = {0.f, 0.f, 0.f, 0.f};
    f32x4 acc[4][4];
#pragma unroll
    for (int i = 0; i < 4; ++i)
#pragma unroll
        for (int j = 0; j < 4; ++j) acc[i][j] = zero;
    float lp0 = 0.f, lp1 = 0.f, lp2 = 0.f, lp3 = 0.f;

    int tt0 = g * 64;   // first 32-key tile of this group
    bf16x8 kf[4];
#pragma unroll
    for (int j = 0; j < 4; ++j)
        kf[j] = *(const bf16x8*)(kbase + (size_t)((tt0 + (j >> 1)) * 32 + (j & 1) * 16 + l15) * 32 + quad * 8);

    // ---- prologue: compute P(0) into buf0 ----
    {
        f32x4 s0 = MFMA16(qf, kf[0], zero);
        f32x4 s1 = MFMA16(qf, kf[1], zero);
        f32x4 s2 = MFMA16(qf, kf[2], zero);
        f32x4 s3 = MFMA16(qf, kf[3], zero);
        float e0[4], e1[4], e2[4], e3[4];
#pragma unroll
        for (int r = 0; r < 4; ++r) {
            e0[r] = __builtin_amdgcn_exp2f(s0[r]);
            e1[r] = __builtin_amdgcn_exp2f(s1[r]);
            e2[r] = __builtin_amdgcn_exp2f(s2[r]);
            e3[r] = __builtin_amdgcn_exp2f(s3[r]);
        }
        lp0 += (e0[0] + e1[0]) + (e2[0] + e3[0]);
        lp1 += (e0[1] + e1[1]) + (e2[1] + e3[1]);
        lp2 += (e0[2] + e1[2]) + (e2[2] + e3[2]);
        lp3 += (e0[3] + e1[3]) + (e2[3] + e3[3]);
        unsigned short* pd = &Plds[g][0][(w * 16 + quad * 4) * 72 + 2 * l15];
#pragma unroll
        for (int r = 0; r < 4; ++r) {
            *(unsigned*)(pd + r * 72)      = pk2bf(e1[r], e0[r]);
            *(unsigned*)(pd + r * 72 + 32) = pk2bf(e3[r], e2[r]);
        }
    }
    // kf <- QK(1) tiles; vfA <- V(0)
#pragma unroll
    for (int j = 0; j < 4; ++j)
        kf[j] = *(const bf16x8*)(kbase + (size_t)((tt0 + 2 + (j >> 1)) * 32 + (j & 1) * 16 + l15) * 32 + quad * 8);
    bf16x8 vfA[2][4], vfB[2][4];
#pragma unroll
    for (int h = 0; h < 2; ++h)
#pragma unroll
        for (int cc = 0; cc < 4; ++cc)
            vfA[h][cc] = *(const bf16x8*)(vbase + (size_t)(tt0 + h) * 8192 + (w * 64 + cc * 16 + l15) * 32 + quad * 8);

    for (int it2 = 0; it2 < 15; ++it2) {
        ATT_PIPE(2 * it2,     vfA, vfB, 1);
        ATT_PIPE(2 * it2 + 1, vfB, vfA, 1);
    }
    ATT_PIPE(30, vfA, vfB, 1);
    ATT_PIPE(31, vfB, vfA, 0);

    // per-group denominator partials
    lp0 += __shfl_xor(lp0, 1); lp0 += __shfl_xor(lp0, 2); lp0 += __shfl_xor(lp0, 4); lp0 += __shfl_xor(lp0, 8);
    lp1 += __shfl_xor(lp1, 1); lp1 += __shfl_xor(lp1, 2); lp1 += __shfl_xor(lp1, 4); lp1 += __shfl_xor(lp1, 8);
    lp2 += __shfl_xor(lp2, 1); lp2 += __shfl_xor(lp2, 2); lp2 += __shfl_xor(lp2, 4); lp2 += __shfl_xor(lp2, 8);
    lp3 += __shfl_xor(lp3, 1); lp3 += __shfl_xor(lp3, 2); lp3 += __shfl_xor(lp3, 4); lp3 += __shfl_xor(lp3, 8);
    if (l15 == 0) {
        int base = w * 16 + quad * 4;
        denl[g][base + 0] = lp0; denl[g][base + 1] = lp1;
        denl[g][base + 2] = lp2; denl[g][base + 3] = lp3;
    }
    if (g == 1) {
#pragma unroll
        for (int qc = 0; qc < 4; ++qc)
#pragma unroll
            for (int cc = 0; cc < 4; ++cc)
                *(f32x4*)&mrg[w * 64 + cc * 16 + l15][qc * 16 + quad * 4] = acc[qc][cc];
    }
    __syncthreads();

    if (g == 0) {
        float gam = gamma[0];
#pragma unroll
        for (int qc = 0; qc < 4; ++qc) {
            int qb = qc * 16 + quad * 4;
            float4 d0 = *(const float4*)&denl[0][qb];
            float4 d1 = *(const float4*)&denl[1][qb];
            float r0 = gam / (d0.x + d1.x), r1 = gam / (d0.y + d1.y);
            float r2 = gam / (d0.z + d1.z), r3 = gam / (d0.w + d1.w);
#pragma unroll
            for (int cc = 0; cc < 4; ++cc) {
                int ch = w * 64 + cc * 16 + l15;
                f32x4 part = *(const f32x4*)&mrg[ch][qb];
                size_t off = ((size_t)(b * NC + ch)) * NSP + m0 + qb;
                float4 e = *(const float4*)(ef + off);
                float4 o;
                o.x = (acc[qc][cc][0] + part[0]) * r0 + e.x;
                o.y = (acc[qc][cc][1] + part[1]) * r1 + e.y;
                o.z = (acc[qc][cc][2] + part[2]) * r2 + e.z;
                o.w = (acc[qc][cc][3] + part[3]) * r3 + e.w;
                *(float4*)(out + off) = o;
            }
        }
    }
}

// ---------------------------------------------------------------------------
extern "C" void kernel_launch(void* const* d_in, const int* in_sizes, int n_in,
                              void* d_out, int out_size, void* d_ws, size_t ws_size,
                              hipStream_t stream) {
    const float* ef    = (const float*)d_in[0];
    const float* sf    = (const float*)d_in[1];
    const float* attn  = (const float*)d_in[2];
    const float* Qw    = (const float*)d_in[3];
    const float* Qb    = (const float*)d_in[4];
    const float* Kw    = (const float*)d_in[5];
    const float* Kb    = (const float*)d_in[6];
    const float* Vw    = (const float*)d_in[7];
    const float* Vb    = (const float*)d_in[8];
    const float* gamma = (const float*)d_in[9];
    float* out = (float*)d_out;

    // workspace carve (~10.8 MB)
    unsigned short* qws  = (unsigned short*)d_ws;                    // 4*4096*32
    unsigned short* kws  = qws + (size_t)4 * 4096 * 32;              // 4*4096*32
    unsigned short* vws  = kws + (size_t)4 * 4096 * 32;              // 4*128*256*32
    unsigned short* Qwbf = vws + (size_t)4 * 128 * 256 * 32;         // 32*512
    unsigned short* Kwbf = Qwbf + 32 * 512;                          // 32*256
    unsigned short* Vwbf = Kwbf + 32 * 256;                          // 256*512

    hipLaunchKernelGGL(prep_w, dim3(64), dim3(256), 0, stream,
                       Qw, Kw, Vw, Qwbf, Kwbf, Vwbf);
    hipLaunchKernelGGL(proj_qv, dim3(128, 4), dim3(256), 0, stream,
                       ef, sf, Qwbf, Qb, Vwbf, Vb, qws, vws);
    hipLaunchKernelGGL(proj_k, dim3(128, 4), dim3(256), 0, stream,
                       attn, Kwbf, Kb, kws);
    hipLaunchKernelGGL(attention, dim3(256), dim3(512), 0, stream,
                       qws, kws, vws, ef, gamma, out);
}